// Round 8
// baseline (100.373 us; speedup 1.0000x reference)
//
#include <hip/hip_runtime.h>

#define NEXP 5
#define MAXF 128
#define NOUT 512
#define PERMOFF 64

typedef __attribute__((ext_vector_type(8))) short short8;
typedef __attribute__((ext_vector_type(4))) float floatx4;

__device__ __forceinline__ ushort f2bf(float f) {   // RNE fp32->bf16
    uint u = __float_as_uint(f);
    u += 0x7FFF + ((u >> 16) & 1);
    return (ushort)(u >> 16);
}

// ws ints: [8..12] = per-expert scatter cursors (== counts when done; memset 0),
// [PERMOFF + e*n + i] = perm (fixed per-expert segment bases, no prefix needed).
// Then 256B-aligned: Wb bf16[5][4][32][64][8] (fragment order, zero-padded past K),
// then xb bf16[n][128].

// blocks [0,nb): scatter-direct; [nb,nb+160): W pack; rest: x fp32->bf16.
__global__ __launch_bounds__(256) void misl_prep(
    const int* __restrict__ feat, const float* __restrict__ x,
    const float* __restrict__ w, int* __restrict__ ws,
    ushort* __restrict__ wb, ushort* __restrict__ xb, int n, int nb) {
    const int tid = threadIdx.x;
    if ((int)blockIdx.x < nb) {
        __shared__ int lcnt[NEXP], lbase[NEXP];
        if (tid < NEXP) lcnt[tid] = 0;
        __syncthreads();
        const int t = blockIdx.x * 256 + tid;
        int e = 0, r = 0;
        if (t < n) {
            e = __ffs(feat[t]) - 4;     // 8->0,16->1,32->2,64->3,128->4
            r = atomicAdd(&lcnt[e], 1);
        }
        __syncthreads();
        if (tid < NEXP) lbase[tid] = atomicAdd(&ws[8 + tid], lcnt[tid]);
        __syncthreads();
        if (t < n) ws[PERMOFF + e * n + lbase[e] + r] = t;
    } else if ((int)blockIdx.x < nb + 160) {
        const int idx = ((int)blockIdx.x - nb) * 256 + tid;  // 0..40959
        const int lane = idx & 63, nb16 = (idx >> 6) & 31;
        const int s = (idx >> 11) & 3, e = idx >> 13;
        if (e < NEXP) {
            const int ncol = nb16 * 16 + (lane & 15);
            const int k0 = s * 32 + (lane >> 4) * 8;
            const int K = 8 << e;
            const float* wr = w + ((size_t)e * NOUT + ncol) * MAXF + k0;
            short8 v;
            #pragma unroll
            for (int j = 0; j < 8; ++j)
                v[j] = (short)((k0 + j < K) ? f2bf(wr[j]) : (ushort)0);
            *(short8*)(wb + (size_t)idx * 8) = v;
        }
    } else {
        const int idx = ((int)blockIdx.x - nb - 160) * 256 + tid;  // n*16 total
        if (idx < n * 16) {
            const float4 a = *(const float4*)(x + (size_t)idx * 8);
            const float4 c = *(const float4*)(x + (size_t)idx * 8 + 4);
            short8 v;
            v[0] = (short)f2bf(a.x); v[1] = (short)f2bf(a.y);
            v[2] = (short)f2bf(a.z); v[3] = (short)f2bf(a.w);
            v[4] = (short)f2bf(c.x); v[5] = (short)f2bf(c.y);
            v[6] = (short)f2bf(c.z); v[7] = (short)f2bf(c.w);
            *(short8*)(xb + (size_t)idx * 8) = v;
        }
    }
}

// wave = 64 ocols x 16 tokens per trip, 4 trips; 8 waves/block -> 512 cols,
// 64 tokens. MFMA with W in A-slot, x in B-slot: C[row=ocol][col=token] ->
// each lane's 4 acc regs are 4 CONSECUTIVE ocols of one token => dwordx4
// stores, float4 bias init, no shfl.
template <int NS>
__device__ __forceinline__ void mfma_run(
    const ushort* __restrict__ xb, const ushort* __restrict__ wbe,
    const float* __restrict__ be, const int* __restrict__ tokp, int rem,
    int lane, int n_base, float* __restrict__ out) {
    const int t = lane & 15, q = lane >> 4;
    const int nb16 = n_base >> 4;
    short8 wf[NS][4];
    #pragma unroll
    for (int s = 0; s < NS; ++s)
        #pragma unroll
        for (int bi = 0; bi < 4; ++bi)
            wf[s][bi] = *(const short8*)(wbe + ((size_t)(s * 32 + nb16 + bi) * 64 + lane) * 8);
    const float* bp = be + n_base + q * 4;

    if (rem == 64) {                        // fast path: full 64-token group
        int tokv[4];
        #pragma unroll
        for (int g = 0; g < 4; ++g) tokv[g] = tokp[g * 16 + t];
        #pragma unroll
        for (int g = 0; g < 4; ++g) {
            const ushort* xr = xb + (size_t)tokv[g] * MAXF + q * 8;
            floatx4 acc[4];
            #pragma unroll
            for (int bi = 0; bi < 4; ++bi)
                acc[bi] = *(const floatx4*)(bp + bi * 16);
            #pragma unroll
            for (int s = 0; s < NS; ++s) {
                const short8 af = *(const short8*)(xr + s * 32);
                #pragma unroll
                for (int bi = 0; bi < 4; ++bi)
                    acc[bi] = __builtin_amdgcn_mfma_f32_16x16x32_bf16(wf[s][bi], af, acc[bi], 0, 0, 0);
            }
            float* orow = out + (size_t)tokv[g] * NOUT + n_base + q * 4;
            #pragma unroll
            for (int bi = 0; bi < 4; ++bi)
                *(floatx4*)(orow + bi * 16) = acc[bi];
        }
    } else {                                // tail: partial group
        const int trips = (rem + 15) >> 4;
        for (int g = 0; g < trips; ++g) {
            const int base = g * 16;
            const int lim = rem - base;     // >= 1
            const int idx = (t < lim) ? t : lim - 1;
            const int tokv = tokp[base + idx];
            const ushort* xr = xb + (size_t)tokv * MAXF + q * 8;
            floatx4 acc[4];
            #pragma unroll
            for (int bi = 0; bi < 4; ++bi)
                acc[bi] = *(const floatx4*)(bp + bi * 16);
            #pragma unroll
            for (int s = 0; s < NS; ++s) {
                const short8 af = *(const short8*)(xr + s * 32);
                #pragma unroll
                for (int bi = 0; bi < 4; ++bi)
                    acc[bi] = __builtin_amdgcn_mfma_f32_16x16x32_bf16(wf[s][bi], af, acc[bi], 0, 0, 0);
            }
            if (t < lim) {
                float* orow = out + (size_t)tokv * NOUT + n_base + q * 4;
                #pragma unroll
                for (int bi = 0; bi < 4; ++bi)
                    *(floatx4*)(orow + bi * 16) = acc[bi];
            }
        }
    }
}

__global__ __launch_bounds__(512) void misl_main(
    const ushort* __restrict__ xb, const ushort* __restrict__ wb,
    const float* __restrict__ b, const int* __restrict__ ws,
    float* __restrict__ out, int n) {
    const int g = blockIdx.x;
    const int c[NEXP] = {ws[8], ws[9], ws[10], ws[11], ws[12]};

    int gb = 0, e = -1, lgs = 0;                // heavy experts first
    #pragma unroll
    for (int j = 0; j < NEXP; ++j) {
        const int ee = 4 - j;
        const int ng = (c[ee] + 63) >> 6;
        if (e < 0 && g < gb + ng) { e = ee; lgs = g - gb; }
        gb += ng;
    }
    if (e < 0) return;

    int rem = c[e] - lgs * 64;
    if (rem > 64) rem = 64;
    const int* tokp = ws + PERMOFF + e * n + lgs * 64;
    const int lane = threadIdx.x & 63;
    const int wave = threadIdx.x >> 6;          // 0..7
    const int n_base = wave * 64;
    const ushort* wbe = wb + (size_t)e * 4 * 32 * 64 * 8;
    const float* be = b + e * NOUT;

    switch (e) {
        case 0: mfma_run<1>(xb, wbe, be, tokp, rem, lane, n_base, out); break;
        case 1: mfma_run<1>(xb, wbe, be, tokp, rem, lane, n_base, out); break;
        case 2: mfma_run<1>(xb, wbe, be, tokp, rem, lane, n_base, out); break;
        case 3: mfma_run<2>(xb, wbe, be, tokp, rem, lane, n_base, out); break;
        case 4: mfma_run<4>(xb, wbe, be, tokp, rem, lane, n_base, out); break;
    }
}

extern "C" void kernel_launch(void* const* d_in, const int* in_sizes, int n_in,
                              void* d_out, int out_size, void* d_ws, size_t ws_size,
                              hipStream_t stream) {
    const float* x    = (const float*)d_in[0];
    const int*   feat = (const int*)d_in[1];
    const float* w    = (const float*)d_in[2];
    const float* b    = (const float*)d_in[3];
    float* out = (float*)d_out;
    int*   ws  = (int*)d_ws;

    const int n  = in_sizes[1];                   // tokens = 32768
    const int nb = (n + 255) / 256;               // 128

    const size_t wb_off = (((size_t)(PERMOFF + (size_t)NEXP * n) * 4) + 255) & ~(size_t)255;
    ushort* wb = (ushort*)((char*)d_ws + wb_off);             // 655 KB
    const size_t xb_off = (wb_off + (size_t)NEXP * 4 * 32 * 64 * 8 * 2 + 255) & ~(size_t)255;
    ushort* xb = (ushort*)((char*)d_ws + xb_off);             // 8.4 MB

    hipMemsetAsync(ws, 0, 64 * sizeof(int), stream);          // zero cursors
    const int cvb = (n * 16 + 255) / 256;                     // 2048
    misl_prep<<<nb + 160 + cvb, 256, 0, stream>>>(feat, x, w, ws, wb, xb, n, nb);
    misl_main<<<(n + 63) / 64 + NEXP, 512, 0, stream>>>(xb, wb, b, ws, out, n);
}